// Round 5
// baseline (193.137 us; speedup 1.0000x reference)
//
#include <hip/hip_runtime.h>
#include <hip/hip_cooperative_groups.h>

namespace cg = cooperative_groups;

#define THRESH 0.5f

// ---------------- zero-init bestbox/hists/scalars
__global__ void k_zero(unsigned* __restrict__ p, int n) {
    int i = blockIdx.x * blockDim.x + threadIdx.x;
    if (i < n) p[i] = 0u;
}

// ---------------- fused: per-anchor match (argmax over boxes) + per-box best anchor
// Division-free: iou_k > iou_b  <=>  inter_k*S_b > inter_b*S_k  (S = area_a + area_b),
// since the inter_k*inter_b cross terms cancel exactly. iou >= 0.5 <=> 3*inter >= S.
__global__ void __launch_bounds__(256) k_matchboth(
        const float* __restrict__ boxes, const float* __restrict__ dflt,
        unsigned* __restrict__ match, unsigned long long* __restrict__ bestbox,
        int B, int A, int M, int chunks) {
    __shared__ float4 bx[128];
    __shared__ float barea[128];
    __shared__ float4 anch[256];
    __shared__ float adarea[256];
    __shared__ unsigned long long lm[128];
    int tid = threadIdx.x;
    int b = blockIdx.x / chunks;
    int chunk = blockIdx.x - b * chunks;
    int a = chunk * 256 + tid;
    if (tid < M) {
        float4 bv = *reinterpret_cast<const float4*>(boxes + ((size_t)b * M + tid) * 4);
        bx[tid] = bv;
        barea[tid] = (bv.z - bv.x) * (bv.w - bv.y);
        lm[tid] = 0ull;
    }
    bool aval = (a < A);
    float dx1 = 0.f, dy1 = 0.f, dx2 = 0.f, dy2 = 0.f, darea = 0.f;
    if (aval) {
        float4 dv = *reinterpret_cast<const float4*>(dflt + (size_t)a * 4);
        dx1 = dv.x - dv.z * 0.5f; dy1 = dv.y - dv.w * 0.5f;
        dx2 = dv.x + dv.z * 0.5f; dy2 = dv.y + dv.w * 0.5f;
        darea = (dx2 - dx1) * (dy2 - dy1);
    }
    anch[tid] = make_float4(dx1, dy1, dx2, dy2);
    adarea[tid] = darea;
    __syncthreads();
    // phase 1: thread = anchor, loop over boxes (LDS broadcast)
    if (aval) {
        float binter = -1.0f, bS = 1.0f; int bm = 0;
        #pragma unroll 4
        for (int m = 0; m < M; ++m) {
            float4 bb = bx[m];
            float lx = fmaxf(bb.x, dx1), ly = fmaxf(bb.y, dy1);
            float rx = fminf(bb.z, dx2), ry = fminf(bb.w, dy2);
            float w = fmaxf(rx - lx, 0.f), h = fmaxf(ry - ly, 0.f);
            float inter = w * h;
            float S = barea[m] + darea;
            bool gt = inter * bS > binter * S;   // strict >: first max kept
            binter = gt ? inter : binter;
            bS     = gt ? S : bS;
            bm     = gt ? m : bm;
        }
        unsigned fl = (3.0f * binter >= bS) ? (1u << 30) : 0u;  // iou >= 0.5
        match[(size_t)b * A + a] = (unsigned)bm | fl;
    }
    // phase 2: lane = box, wave scans its 64 anchors (LDS broadcast reads)
    int wv = tid >> 6, lane = tid & 63;
    int abase = chunk * 256 + wv * 64;
    int kmax = min(64, A - abase);
    if (lane < M && kmax > 0) {
        float4 bb = bx[lane];
        float ba = barea[lane];
        float binter = -1.0f, bS = 1.0f; int bk = 0;
        #pragma unroll 4
        for (int k = 0; k < kmax; ++k) {
            float4 av = anch[wv * 64 + k];
            float lx = fmaxf(bb.x, av.x), ly = fmaxf(bb.y, av.y);
            float rx = fminf(bb.z, av.z), ry = fminf(bb.w, av.w);
            float w = fmaxf(rx - lx, 0.f), h = fmaxf(ry - ly, 0.f);
            float inter = w * h;
            float S = ba + adarea[wv * 64 + k];
            bool gt = inter * bS > binter * S;
            binter = gt ? inter : binter;
            bS     = gt ? S : bS;
            bk     = gt ? k : bk;
        }
        float best = binter / (bS - binter);     // one div per lane (ordering key)
        atomicMax(&lm[lane], ((unsigned long long)__float_as_uint(best) << 32) |
                             (unsigned long long)(unsigned)(~(abase + bk)));
    }
    __syncthreads();
    if (tid < M) {
        unsigned long long p = lm[tid];
        if (p) atomicMax(&bestbox[(size_t)b * M + tid], p);
    }
}

// ---------------- apply force-match override (last box wins via max m)
__global__ void k_override(const unsigned long long* __restrict__ bestbox,
                           unsigned* __restrict__ match, int B, int A, int M) {
    int i = blockIdx.x * blockDim.x + threadIdx.x;
    if (i >= B * M) return;
    unsigned long long p = bestbox[i];
    unsigned a = ~(unsigned)(p & 0xFFFFFFFFull);
    if (a < (unsigned)A) {
        int b = i / M, m = i % M;
        atomicMax(&match[(size_t)b * A + a], 0x80000000u | (unsigned)m);
    }
}

// ---------------- main fused pass, 4 elements/thread, one batch per block
__global__ void __launch_bounds__(256) k_main(
        const float* __restrict__ x, const float* __restrict__ y,
        const float* __restrict__ boxes, const int* __restrict__ labels,
        const float* __restrict__ dflt, const unsigned* __restrict__ match,
        float* __restrict__ negv, unsigned* __restrict__ hist1,
        unsigned* __restrict__ scal, int A, int M, int N) {
    __shared__ unsigned lh[2048];
    __shared__ float4 sbx[128];
    __shared__ int slab[128];
    for (int j = threadIdx.x; j < 2048; j += 256) lh[j] = 0u;
    int i0 = (blockIdx.x * 256 + threadIdx.x) * 4;
    int b = (int)(((long long)blockIdx.x * 1024) / A);  // block spans one batch (A % 1024 == 0)
    if (threadIdx.x < M) {
        sbx[threadIdx.x] = *reinterpret_cast<const float4*>(boxes + ((size_t)b * M + threadIdx.x) * 4);
        slab[threadIdx.x] = labels[b * M + threadIdx.x];
    }
    __syncthreads();
    float l_smooth = 0.f, l_pos = 0.f; int l_cnt = 0;
    if (i0 + 3 < N) {
        int a0 = i0 - b * A;
        uint4 w4 = *reinterpret_cast<const uint4*>(match + i0);
        const float4* xp = reinterpret_cast<const float4*>(x + (size_t)i0 * 4);
        float4 xs[4] = {xp[0], xp[1], xp[2], xp[3]};
        const float4* yp = reinterpret_cast<const float4*>(y + (size_t)i0 * 2);
        float4 ya = yp[0], yb = yp[1];
        const float4* dp = reinterpret_cast<const float4*>(dflt + (size_t)a0 * 4);
        float4 ds[4] = {dp[0], dp[1], dp[2], dp[3]};
        unsigned wws[4] = {w4.x, w4.y, w4.z, w4.w};
        float y0s[4] = {ya.x, ya.z, yb.x, yb.z};
        float y1s[4] = {ya.y, ya.w, yb.y, yb.w};
        float vs[4];
        #pragma unroll
        for (int e = 0; e < 4; ++e) {
            unsigned w = wws[e];
            int digit = (int)(w & 0xFFFFu);
            bool flag = (w & 0xC0000000u) != 0u;   // override(bit31) or overlap>=thr(bit30)
            int c = flag ? slab[digit] : 0;
            bool pos = (c == 1);
            float4 bv = sbx[digit];
            float4 dv = ds[e];
            float cw = bv.z - bv.x, ch = bv.w - bv.y;
            float ccx = (bv.x + bv.z) * 0.5f, ccy = (bv.y + bv.w) * 0.5f;
            float l0 = (ccx - dv.x) / (dv.z * 0.1f);
            float l1 = (ccy - dv.y) / (dv.w * 0.1f);
            float l2 = logf(cw / dv.z) * 5.f;
            float l3 = logf(ch / dv.w) * 5.f;
            float4 xv = xs[e];
            float s = 0.f, d, ad;
            d = xv.x - l0; ad = fabsf(d); s += (ad < 1.f) ? 0.5f * d * d : ad - 0.5f;
            d = xv.y - l1; ad = fabsf(d); s += (ad < 1.f) ? 0.5f * d * d : ad - 0.5f;
            d = xv.z - l2; ad = fabsf(d); s += (ad < 1.f) ? 0.5f * d * d : ad - 0.5f;
            d = xv.w - l3; ad = fabsf(d); s += (ad < 1.f) ? 0.5f * d * d : ad - 0.5f;
            float y0 = y0s[e], y1v = y1s[e];
            float mx = fmaxf(y0, y1v);
            float lse = mx + logf(expf(y0 - mx) + expf(y1v - mx));
            float ent = lse - ((c == 0) ? y0 : y1v);
            float v = pos ? 0.f : ent;
            vs[e] = v;
            if (pos) { l_smooth += s; l_pos += ent; l_cnt += 1; }
            atomicAdd(&lh[__float_as_uint(v) >> 21], 1u);
        }
        *reinterpret_cast<float4*>(negv + i0) = make_float4(vs[0], vs[1], vs[2], vs[3]);
    }
    for (int off = 32; off > 0; off >>= 1) {
        l_smooth += __shfl_down(l_smooth, off, 64);
        l_pos    += __shfl_down(l_pos, off, 64);
        l_cnt    += __shfl_down(l_cnt, off, 64);
    }
    __shared__ float rs[4], rp[4]; __shared__ int rc[4];
    int wv = threadIdx.x >> 6;
    if ((threadIdx.x & 63) == 0) { rs[wv] = l_smooth; rp[wv] = l_pos; rc[wv] = l_cnt; }
    __syncthreads();
    if (threadIdx.x == 0) {
        float ss = rs[0] + rs[1] + rs[2] + rs[3];
        float pp = rp[0] + rp[1] + rp[2] + rp[3];
        int   cc = rc[0] + rc[1] + rc[2] + rc[3];
        if (ss != 0.f) atomicAdd((float*)&scal[2], ss);
        if (pp != 0.f) atomicAdd((float*)&scal[1], pp);
        if (cc)        atomicAdd((int*)&scal[0], cc);
    }
    __syncthreads();
    for (int j = threadIdx.x; j < 2048; j += 256) {
        unsigned h = lh[j];
        if (h) atomicAdd(&hist1[j], h);
    }
}

// ---------------- block-cooperative: find bin containing k-th largest in hist
__device__ __forceinline__ void scan_find(const unsigned* __restrict__ hist, int nbins,
                                          unsigned k, unsigned* ts, unsigned* res) {
    int t = threadIdx.x;
    int per = nbins >> 8;
    unsigned s = 0;
    for (int j = 0; j < per; ++j) s += hist[t * per + j];
    ts[t] = s;
    __syncthreads();
    for (int off = 1; off < 256; off <<= 1) {
        unsigned add = (t >= off) ? ts[t - off] : 0u;
        __syncthreads();
        ts[t] += add;
        __syncthreads();
    }
    unsigned total = ts[255];
    unsigned P = (t == 0) ? 0u : ts[t - 1];
    for (int j = 0; j < per; ++j) {
        unsigned h = hist[t * per + j];
        P += h;
        unsigned above = total - P;
        if (above < k && k <= above + h) { res[0] = (unsigned)(t * per + j); res[1] = k - above; }
    }
    __syncthreads();
}

// ---------------- cooperative tail: level-2 refine, top-k sum, finalize.
// Tied level-2 bin approximated by bin midpoint: error <= k2 * 2^-13 rel — negligible.
__global__ void __launch_bounds__(256) k_tail(
        const float* __restrict__ negv, int N, unsigned* __restrict__ scal,
        const unsigned* __restrict__ hist1, unsigned* __restrict__ hist2,
        float* __restrict__ out) {
    cg::grid_group grid = cg::this_grid();
    __shared__ unsigned ts[256], res[2], lh[2048];
    scan_find(hist1, 2048, scal[0], ts, res);
    unsigned bin1 = res[0], k1 = res[1];
    for (int j = threadIdx.x; j < 2048; j += 256) lh[j] = 0u;
    __syncthreads();
    for (int i = (blockIdx.x * 256 + threadIdx.x) * 4; i < N; i += gridDim.x * 1024) {
        float4 v4 = *reinterpret_cast<const float4*>(negv + i);
        unsigned u;
        u = __float_as_uint(v4.x); if ((u >> 21) == bin1) atomicAdd(&lh[(u >> 10) & 0x7FFu], 1u);
        u = __float_as_uint(v4.y); if ((u >> 21) == bin1) atomicAdd(&lh[(u >> 10) & 0x7FFu], 1u);
        u = __float_as_uint(v4.z); if ((u >> 21) == bin1) atomicAdd(&lh[(u >> 10) & 0x7FFu], 1u);
        u = __float_as_uint(v4.w); if ((u >> 21) == bin1) atomicAdd(&lh[(u >> 10) & 0x7FFu], 1u);
    }
    __syncthreads();
    for (int j = threadIdx.x; j < 2048; j += 256) {
        unsigned h = lh[j];
        if (h) atomicAdd(&hist2[j], h);
    }
    grid.sync();
    // level-2 scan + sum of everything strictly above bin2
    scan_find(hist2, 2048, k1, ts, res);
    unsigned bin2 = res[0], k2 = res[1];
    unsigned tb = (bin1 << 21) | (bin2 << 10) | 0x3FFu;  // top of bin2 (inclusive bound)
    float s = 0.f;
    for (int i = (blockIdx.x * 256 + threadIdx.x) * 4; i < N; i += gridDim.x * 1024) {
        float4 v4 = *reinterpret_cast<const float4*>(negv + i);
        unsigned u;
        u = __float_as_uint(v4.x); if (u > tb) s += v4.x;
        u = __float_as_uint(v4.y); if (u > tb) s += v4.y;
        u = __float_as_uint(v4.z); if (u > tb) s += v4.z;
        u = __float_as_uint(v4.w); if (u > tb) s += v4.w;
    }
    for (int off = 32; off > 0; off >>= 1) s += __shfl_down(s, off, 64);
    __shared__ float rsum[4];
    int wv = threadIdx.x >> 6;
    if ((threadIdx.x & 63) == 0) rsum[wv] = s;
    __syncthreads();
    if (threadIdx.x == 0) {
        float ss = rsum[0] + rsum[1] + rsum[2] + rsum[3];
        if (ss != 0.f) atomicAdd((float*)&scal[9], ss);
    }
    grid.sync();
    if (blockIdx.x == 0 && threadIdx.x == 0) {
        volatile unsigned* vs = scal;
        volatile float* vf = (volatile float*)scal;
        float k = (float)vs[0];
        float tmid = __uint_as_float((bin1 << 21) | (bin2 << 10) | 512u);
        float neg_sum = vf[9] + (float)k2 * tmid;
        float smooth = vf[2] / (k * 4.f);
        float ent = (vf[1] + neg_sum) / k;
        out[0] = smooth + ent;
    }
}

extern "C" void kernel_launch(void* const* d_in, const int* in_sizes, int n_in,
                              void* d_out, int out_size, void* d_ws, size_t ws_size,
                              hipStream_t stream) {
    const float* x      = (const float*)d_in[0];
    const float* y      = (const float*)d_in[1];
    const float* boxes  = (const float*)d_in[2];
    const int*   labels = (const int*)d_in[3];
    const float* dflt   = (const float*)d_in[4];
    float* out = (float*)d_out;

    int A = in_sizes[4] / 4;
    int B = in_sizes[1] / (2 * A);
    int M = in_sizes[3] / B;
    int N = B * A;

    unsigned* ws    = (unsigned*)d_ws;
    unsigned* match = ws;                                       // N u32
    float*    negv  = (float*)(ws + (size_t)N);                 // N f32
    unsigned long long* bestbox = (unsigned long long*)(ws + (size_t)2 * N);  // B*M u64
    unsigned* hist1 = ws + (size_t)2 * N + 2 * B * M;           // 2048
    unsigned* hist2 = hist1 + 2048;                             // 2048
    unsigned* scal  = hist2 + 2048;                             // 16
    int nzero = 2 * B * M + 2048 + 2048 + 16;

    int chunks = (A + 255) / 256;
    k_zero<<<dim3((nzero + 255) / 256), dim3(256), 0, stream>>>(ws + (size_t)2 * N, nzero);
    k_matchboth<<<dim3(B * chunks), dim3(256), 0, stream>>>(boxes, dflt, match, bestbox, B, A, M, chunks);
    k_override<<<dim3((B * M + 255) / 256), dim3(256), 0, stream>>>(bestbox, match, B, A, M);
    k_main<<<dim3(N / 1024), dim3(256), 0, stream>>>(x, y, boxes, labels, dflt, match,
                                                     negv, hist1, scal, A, M, N);
    void* args[] = { (void*)&negv, (void*)&N, (void*)&scal,
                     (void*)&hist1, (void*)&hist2, (void*)&out };
    hipLaunchCooperativeKernel((const void*)k_tail, dim3(256), dim3(256), args, 0, stream);
}

// Round 6
// 153.856 us; speedup vs baseline: 1.2553x; 1.2553x over previous
//
#include <hip/hip_runtime.h>

#define THRESH 0.5f

// ---------------- fused: per-anchor match (argmax over boxes) + per-box best anchor
// Division-free: iou_k > iou_b  <=>  inter_k*S_b > inter_b*S_k  (S = area_a + area_b).
// iou >= 0.5 <=> 3*inter >= S. Phase 2 writes per-chunk packed results (no atomics,
// no pre-zero). Block 0 additionally zeroes hist1/hist2/scal (4112 words).
__global__ void __launch_bounds__(256) k_matchboth(
        const float* __restrict__ boxes, const float* __restrict__ dflt,
        unsigned* __restrict__ match, unsigned long long* __restrict__ bestchunk,
        unsigned* __restrict__ zerop, int B, int A, int M, int chunks) {
    __shared__ float4 bx[128];
    __shared__ float barea[128];
    __shared__ float4 anch[256];
    __shared__ float adarea[256];
    __shared__ unsigned long long lm[128];
    int tid = threadIdx.x;
    if (blockIdx.x == 0) {
        for (int j = tid; j < 4112; j += 256) zerop[j] = 0u;
    }
    int b = blockIdx.x / chunks;
    int chunk = blockIdx.x - b * chunks;
    int a = chunk * 256 + tid;
    if (tid < M) {
        float4 bv = *reinterpret_cast<const float4*>(boxes + ((size_t)b * M + tid) * 4);
        bx[tid] = bv;
        barea[tid] = (bv.z - bv.x) * (bv.w - bv.y);
        lm[tid] = 0ull;
    }
    bool aval = (a < A);
    float dx1 = 0.f, dy1 = 0.f, dx2 = 0.f, dy2 = 0.f, darea = 0.f;
    if (aval) {
        float4 dv = *reinterpret_cast<const float4*>(dflt + (size_t)a * 4);
        dx1 = dv.x - dv.z * 0.5f; dy1 = dv.y - dv.w * 0.5f;
        dx2 = dv.x + dv.z * 0.5f; dy2 = dv.y + dv.w * 0.5f;
        darea = (dx2 - dx1) * (dy2 - dy1);
    }
    anch[tid] = make_float4(dx1, dy1, dx2, dy2);
    adarea[tid] = darea;
    __syncthreads();
    // phase 1: thread = anchor, loop over boxes (LDS broadcast)
    if (aval) {
        float binter = -1.0f, bS = 1.0f; int bm = 0;
        #pragma unroll 4
        for (int m = 0; m < M; ++m) {
            float4 bb = bx[m];
            float lx = fmaxf(bb.x, dx1), ly = fmaxf(bb.y, dy1);
            float rx = fminf(bb.z, dx2), ry = fminf(bb.w, dy2);
            float w = fmaxf(rx - lx, 0.f), h = fmaxf(ry - ly, 0.f);
            float inter = w * h;
            float S = barea[m] + darea;
            bool gt = inter * bS > binter * S;   // strict >: first max kept
            binter = gt ? inter : binter;
            bS     = gt ? S : bS;
            bm     = gt ? m : bm;
        }
        unsigned fl = (3.0f * binter >= bS) ? (1u << 30) : 0u;  // iou >= 0.5
        match[(size_t)b * A + a] = (unsigned)bm | fl;
    }
    // phase 2: lane = box, wave scans its 64 anchors (LDS broadcast reads)
    int wv = tid >> 6, lane = tid & 63;
    int abase = chunk * 256 + wv * 64;
    int kmax = min(64, A - abase);
    if (lane < M && kmax > 0) {
        float4 bb = bx[lane];
        float ba = barea[lane];
        float binter = -1.0f, bS = 1.0f; int bk = 0;
        #pragma unroll 4
        for (int k = 0; k < kmax; ++k) {
            float4 av = anch[wv * 64 + k];
            float lx = fmaxf(bb.x, av.x), ly = fmaxf(bb.y, av.y);
            float rx = fminf(bb.z, av.z), ry = fminf(bb.w, av.w);
            float w = fmaxf(rx - lx, 0.f), h = fmaxf(ry - ly, 0.f);
            float inter = w * h;
            float S = ba + adarea[wv * 64 + k];
            bool gt = inter * bS > binter * S;
            binter = gt ? inter : binter;
            bS     = gt ? S : bS;
            bk     = gt ? k : bk;
        }
        float best = binter / (bS - binter);     // one div per lane (ordering key)
        atomicMax(&lm[lane], ((unsigned long long)__float_as_uint(best) << 32) |
                             (unsigned long long)(unsigned)(~(abase + bk)));
    }
    __syncthreads();
    if (tid < M)
        bestchunk[((size_t)b * chunks + chunk) * M + tid] = lm[tid];
}

// ---------------- main fused pass, 4 elements/thread, one batch per block.
// Override folded in: threads<M reduce bestchunk over chunks (L2-hot, 32 KB/batch),
// post into LDS override table (atomicMax on m => last box wins).
__global__ void __launch_bounds__(256) k_main(
        const float* __restrict__ x, const float* __restrict__ y,
        const float* __restrict__ boxes, const int* __restrict__ labels,
        const float* __restrict__ dflt, const unsigned* __restrict__ match,
        const unsigned long long* __restrict__ bestchunk,
        float* __restrict__ negv, unsigned* __restrict__ hist1,
        unsigned* __restrict__ scal, int A, int M, int chunks, int N) {
    __shared__ unsigned lh[2048];
    __shared__ float4 sbx[128];
    __shared__ int slab[128];
    __shared__ int ovr[1024];
    int tid = threadIdx.x;
    for (int j = tid; j < 2048; j += 256) lh[j] = 0u;
    for (int j = tid; j < 1024; j += 256) ovr[j] = -1;
    int i0 = (blockIdx.x * 256 + tid) * 4;
    int base = blockIdx.x * 1024;
    int b = (int)(((long long)blockIdx.x * 1024) / A);  // block spans one batch (A % 1024 == 0)
    if (tid < M) {
        sbx[tid] = *reinterpret_cast<const float4*>(boxes + ((size_t)b * M + tid) * 4);
        slab[tid] = labels[b * M + tid];
    }
    __syncthreads();
    if (tid < M) {
        unsigned long long p = 0ull;
        const unsigned long long* bp = bestchunk + (size_t)b * chunks * M + tid;
        for (int c = 0; c < chunks; ++c) {
            unsigned long long q = bp[(size_t)c * M];
            p = (q > p) ? q : p;
        }
        unsigned a = ~(unsigned)(p & 0xFFFFFFFFull);
        int target = b * A + (int)a;
        if (target >= base && target < base + 1024)
            atomicMax(&ovr[target - base], tid);   // max m => last box wins
    }
    __syncthreads();
    float l_smooth = 0.f, l_pos = 0.f; int l_cnt = 0;
    if (i0 + 3 < N) {
        uint4 w4 = *reinterpret_cast<const uint4*>(match + i0);
        const float4* yp = reinterpret_cast<const float4*>(y + (size_t)i0 * 2);
        float4 ya = yp[0], yb = yp[1];
        unsigned wws[4] = {w4.x, w4.y, w4.z, w4.w};
        float y0s[4] = {ya.x, ya.z, yb.x, yb.z};
        float y1s[4] = {ya.y, ya.w, yb.y, yb.w};
        float vs[4];
        int a0 = i0 - b * A;
        #pragma unroll
        for (int e = 0; e < 4; ++e) {
            unsigned w = wws[e];
            int digit = (int)(w & 0xFFFFu);
            bool flag = (w & 0x40000000u) != 0u;
            int o = ovr[tid * 4 + e];
            if (o >= 0) { digit = o; flag = true; }   // forced match
            int c = flag ? slab[digit] : 0;
            bool pos = (c == 1);
            float y0 = y0s[e], y1v = y1s[e];
            float mx = fmaxf(y0, y1v);
            float lse = mx + log1pf(expf(-fabsf(y0 - y1v)));
            float ent = lse - ((c == 0) ? y0 : y1v);
            float v = pos ? 0.f : ent;
            vs[e] = v;
            if (pos) {
                // smooth-L1 only contributes for positives (rare)
                float4 bv = sbx[digit];
                float4 dv = *reinterpret_cast<const float4*>(dflt + (size_t)(a0 + e) * 4);
                float4 xv = *reinterpret_cast<const float4*>(x + (size_t)(i0 + e) * 4);
                float cw = bv.z - bv.x, ch = bv.w - bv.y;
                float ccx = (bv.x + bv.z) * 0.5f, ccy = (bv.y + bv.w) * 0.5f;
                float l0 = (ccx - dv.x) / (dv.z * 0.1f);
                float l1 = (ccy - dv.y) / (dv.w * 0.1f);
                float l2 = logf(cw / dv.z) * 5.f;
                float l3 = logf(ch / dv.w) * 5.f;
                float s = 0.f, d, ad;
                d = xv.x - l0; ad = fabsf(d); s += (ad < 1.f) ? 0.5f * d * d : ad - 0.5f;
                d = xv.y - l1; ad = fabsf(d); s += (ad < 1.f) ? 0.5f * d * d : ad - 0.5f;
                d = xv.z - l2; ad = fabsf(d); s += (ad < 1.f) ? 0.5f * d * d : ad - 0.5f;
                d = xv.w - l3; ad = fabsf(d); s += (ad < 1.f) ? 0.5f * d * d : ad - 0.5f;
                l_smooth += s; l_pos += ent; l_cnt += 1;
            }
            atomicAdd(&lh[__float_as_uint(v) >> 21], 1u);
        }
        *reinterpret_cast<float4*>(negv + i0) = make_float4(vs[0], vs[1], vs[2], vs[3]);
    }
    for (int off = 32; off > 0; off >>= 1) {
        l_smooth += __shfl_down(l_smooth, off, 64);
        l_pos    += __shfl_down(l_pos, off, 64);
        l_cnt    += __shfl_down(l_cnt, off, 64);
    }
    __shared__ float rs[4], rp[4]; __shared__ int rc[4];
    int wv = tid >> 6;
    if ((tid & 63) == 0) { rs[wv] = l_smooth; rp[wv] = l_pos; rc[wv] = l_cnt; }
    __syncthreads();
    if (tid == 0) {
        float ss = rs[0] + rs[1] + rs[2] + rs[3];
        float pp = rp[0] + rp[1] + rp[2] + rp[3];
        int   cc = rc[0] + rc[1] + rc[2] + rc[3];
        if (ss != 0.f) atomicAdd((float*)&scal[2], ss);
        if (pp != 0.f) atomicAdd((float*)&scal[1], pp);
        if (cc)        atomicAdd((int*)&scal[0], cc);
    }
    __syncthreads();
    for (int j = tid; j < 2048; j += 256) {
        unsigned h = lh[j];
        if (h) atomicAdd(&hist1[j], h);
    }
}

// ---------------- block-cooperative: find bin containing k-th largest in hist
__device__ __forceinline__ void scan_find(const unsigned* __restrict__ hist, int nbins,
                                          unsigned k, unsigned* ts, unsigned* res) {
    int t = threadIdx.x;
    int per = nbins >> 8;
    unsigned s = 0;
    for (int j = 0; j < per; ++j) s += hist[t * per + j];
    ts[t] = s;
    __syncthreads();
    for (int off = 1; off < 256; off <<= 1) {
        unsigned add = (t >= off) ? ts[t - off] : 0u;
        __syncthreads();
        ts[t] += add;
        __syncthreads();
    }
    unsigned total = ts[255];
    unsigned P = (t == 0) ? 0u : ts[t - 1];
    for (int j = 0; j < per; ++j) {
        unsigned h = hist[t * per + j];
        P += h;
        unsigned above = total - P;
        if (above < k && k <= above + h) { res[0] = (unsigned)(t * per + j); res[1] = k - above; }
    }
    __syncthreads();
}

// ---------------- level-2 refine (scans hist1 inline)
__global__ void __launch_bounds__(256) k_refine2(
        const float* __restrict__ negv, int N, const unsigned* __restrict__ scal,
        const unsigned* __restrict__ hist1, unsigned* __restrict__ hist2) {
    __shared__ unsigned ts[256], res[2], lh[2048];
    scan_find(hist1, 2048, scal[0], ts, res);
    unsigned bin1 = res[0];
    for (int j = threadIdx.x; j < 2048; j += 256) lh[j] = 0u;
    __syncthreads();
    for (int i = (blockIdx.x * 256 + threadIdx.x) * 4; i < N; i += gridDim.x * 1024) {
        float4 v4 = *reinterpret_cast<const float4*>(negv + i);
        unsigned u;
        u = __float_as_uint(v4.x); if ((u >> 21) == bin1) atomicAdd(&lh[(u >> 10) & 0x7FFu], 1u);
        u = __float_as_uint(v4.y); if ((u >> 21) == bin1) atomicAdd(&lh[(u >> 10) & 0x7FFu], 1u);
        u = __float_as_uint(v4.z); if ((u >> 21) == bin1) atomicAdd(&lh[(u >> 10) & 0x7FFu], 1u);
        u = __float_as_uint(v4.w); if ((u >> 21) == bin1) atomicAdd(&lh[(u >> 10) & 0x7FFu], 1u);
    }
    __syncthreads();
    for (int j = threadIdx.x; j < 2048; j += 256) {
        unsigned h = lh[j];
        if (h) atomicAdd(&hist2[j], h);
    }
}

// ---------------- sum above threshold + last-block finalize.
// Tied level-2 bin approximated by bin midpoint: error <= k2 * 2^-14 rel — negligible.
__global__ void __launch_bounds__(256) k_sum(
        const float* __restrict__ negv, int N, unsigned* __restrict__ scal,
        const unsigned* __restrict__ hist1, const unsigned* __restrict__ hist2,
        float* __restrict__ out) {
    __shared__ unsigned ts[256], res[2];
    scan_find(hist1, 2048, scal[0], ts, res);
    unsigned bin1 = res[0], k1 = res[1];
    scan_find(hist2, 2048, k1, ts, res);
    unsigned bin2 = res[0], k2 = res[1];
    unsigned tb = (bin1 << 21) | (bin2 << 10) | 0x3FFu;  // top of bin2 (inclusive bound)
    float s = 0.f;
    for (int i = (blockIdx.x * 256 + threadIdx.x) * 4; i < N; i += gridDim.x * 1024) {
        float4 v4 = *reinterpret_cast<const float4*>(negv + i);
        unsigned u;
        u = __float_as_uint(v4.x); if (u > tb) s += v4.x;
        u = __float_as_uint(v4.y); if (u > tb) s += v4.y;
        u = __float_as_uint(v4.z); if (u > tb) s += v4.z;
        u = __float_as_uint(v4.w); if (u > tb) s += v4.w;
    }
    for (int off = 32; off > 0; off >>= 1) s += __shfl_down(s, off, 64);
    __shared__ float rsum[4];
    __shared__ unsigned isLast;
    int wv = threadIdx.x >> 6;
    if ((threadIdx.x & 63) == 0) rsum[wv] = s;
    __syncthreads();
    if (threadIdx.x == 0) {
        float ss = rsum[0] + rsum[1] + rsum[2] + rsum[3];
        if (ss != 0.f) atomicAdd((float*)&scal[9], ss);
        __threadfence();
        unsigned prev = atomicAdd(&scal[12], 1u);
        isLast = (prev == gridDim.x - 1) ? 1u : 0u;
    }
    __syncthreads();
    if (isLast && threadIdx.x == 0) {
        __threadfence();
        volatile unsigned* vs = scal;
        volatile float* vf = (volatile float*)scal;
        float k = (float)vs[0];
        float tmid = __uint_as_float((bin1 << 21) | (bin2 << 10) | 512u);
        float neg_sum = vf[9] + (float)k2 * tmid;
        float smooth = vf[2] / (k * 4.f);
        float ent = (vf[1] + neg_sum) / k;
        out[0] = smooth + ent;
    }
}

extern "C" void kernel_launch(void* const* d_in, const int* in_sizes, int n_in,
                              void* d_out, int out_size, void* d_ws, size_t ws_size,
                              hipStream_t stream) {
    const float* x      = (const float*)d_in[0];
    const float* y      = (const float*)d_in[1];
    const float* boxes  = (const float*)d_in[2];
    const int*   labels = (const int*)d_in[3];
    const float* dflt   = (const float*)d_in[4];
    float* out = (float*)d_out;

    int A = in_sizes[4] / 4;
    int B = in_sizes[1] / (2 * A);
    int M = in_sizes[3] / B;
    int N = B * A;
    int chunks = (A + 255) / 256;

    unsigned* ws    = (unsigned*)d_ws;
    unsigned* match = ws;                                       // N u32
    float*    negv  = (float*)(ws + (size_t)N);                 // N f32
    unsigned long long* bestchunk = (unsigned long long*)(ws + (size_t)2 * N);  // B*chunks*M u64
    unsigned* hist1 = ws + (size_t)2 * N + (size_t)2 * B * chunks * M;  // 2048
    unsigned* hist2 = hist1 + 2048;                             // 2048
    unsigned* scal  = hist2 + 2048;                             // 16

    k_matchboth<<<dim3(B * chunks), dim3(256), 0, stream>>>(boxes, dflt, match, bestchunk,
                                                            hist1, B, A, M, chunks);
    k_main<<<dim3(N / 1024), dim3(256), 0, stream>>>(x, y, boxes, labels, dflt, match, bestchunk,
                                                     negv, hist1, scal, A, M, chunks, N);
    k_refine2<<<dim3(256), dim3(256), 0, stream>>>(negv, N, scal, hist1, hist2);
    k_sum<<<dim3(256), dim3(256), 0, stream>>>(negv, N, scal, hist1, hist2, out);
}